// Round 14
// baseline (151.824 us; speedup 1.0000x reference)
//
#include <hip/hip_runtime.h>
#include <math.h>

#define B_ 2
#define N_ 400
#define F_ 246
#define C_ 32
#define LBL_ 1440
#define NODE_IN_ 310  // F + 2C

#define KX_ 320   // Abuf row: 246 x | 32 aggi | 32 aggj | 10 pad (pad holds
                  // poison; consumer weights there are 0.0 and poison bf16
                  // 0xAAAA is finite -> 0*poison = 0)
#define KN_ 256   // node output cols padded 246 -> 256

#define T_ABUF (800 * KX_)
#define T_WNT  (256 * KX_)
#define T_WOT  (LBL_ * KN_)

#define WL_S 260  // LDS Wl row stride (shorts): 520 B rows, 8B-aligned b64 reads,
                  // bank start = 2n mod 32 -> all 16 lanes distinct, no conflict

typedef __attribute__((ext_vector_type(8))) short bf16x8;  // 8 bf16, 4 VGPRs
typedef __attribute__((ext_vector_type(4))) short bf16x4;
typedef __attribute__((ext_vector_type(4))) float f32x4;

__device__ __forceinline__ short f2bf(float f) {           // RNE fp32->bf16
    unsigned u = __float_as_uint(f);
    return (short)((u + 0x7FFF + ((u >> 16) & 1)) >> 16);
}

// MFMA layouts (HW-verified m89/m120): A[m=lane&15][k=quad*8+j];
// BT row-major [n][k] (8 consecutive k per lane); C/D col=lane&15, row=quad*4+reg.
template <int K>
__device__ __forceinline__ f32x4 mfma_tile(const short* __restrict__ A,
                                           const short* __restrict__ BT,
                                           int m0, int n0, int lane) {
    int r = lane & 15, quad = lane >> 4;
    const short* ap = A + (size_t)(m0 + r) * K + quad * 8;
    const short* bp = BT + (size_t)(n0 + r) * K + quad * 8;
    f32x4 acc = {0.f, 0.f, 0.f, 0.f};
    #pragma unroll
    for (int kk = 0; kk < K; kk += 32) {
        bf16x8 av = *(const bf16x8*)(ap + kk);
        bf16x8 bv = *(const bf16x8*)(bp + kk);
        acc = __builtin_amdgcn_mfma_f32_16x16x32_bf16(av, bv, acc, 0, 0, 0);
    }
    return acc;
}

// ---------------------------------------------------------------------------
// K1 k_pre (one dispatch, block ranges):
//  [0,50):    PQ[800][64] MFMA; B-operand = combined [WsP|WsQ] staged to LDS
//             bf16 (no global W2T buffer, no dependency); A-operand built
//             in-register from fp32 x via aligned float2 loads (bit-identical
//             f2bf numerics; K=256, k>=246 zero both sides).
//  [50,150):  Abuf[row][0:246] = bf16(x), 8 rows/block (agg cols by k_agg)
//  [150,510): WoT[1440][256] = bf16(Wo^T), LDS 32x32 tiles (coalesced R+W)
//  [510,590): WnT[256][320]  = bf16(Wn^T) zero-padded, LDS tiles
// ---------------------------------------------------------------------------
__global__ void k_pre(const float* __restrict__ x, const float* __restrict__ Ws,
                      const float* __restrict__ Wn, const float* __restrict__ Wo,
                      float* __restrict__ PQ, short* __restrict__ Abuf,
                      short* __restrict__ WnT, short* __restrict__ WoT) {
    __shared__ short tile[32][33];        // transpose branch (2 KB)
    __shared__ short Wl[64 * WL_S];       // PQ branch (32.5 KB)
    int bx = blockIdx.x, tid = threadIdx.x;
    if (bx < 50) {                        // ---- PQ MFMA
        for (int idx = tid; idx < 64 * 256; idx += 256) {
            int n = idx >> 8, k = idx & 255;
            float v = 0.f;
            if (k < F_) v = (n < C_) ? Ws[k * C_ + n] : Ws[(F_ + k) * C_ + (n - C_)];
            Wl[n * WL_S + k] = f2bf(v);
        }
        __syncthreads();
        int w = tid >> 6, lane = tid & 63;
        int m0 = bx * 16, r = lane & 15, quad = lane >> 4;
        int n0 = w * 16;
        const float* xrow = x + (size_t)(m0 + r) * F_;    // 8B-aligned rows
        const short* wrow = &Wl[(n0 + r) * WL_S + quad * 8];
        f32x4 acc = {0.f, 0.f, 0.f, 0.f};
        #pragma unroll
        for (int kk = 0; kk < 256; kk += 32) {
            int kb = kk + quad * 8;
            bf16x8 av, bv;
            bf16x4 b0 = *(const bf16x4*)(wrow + kk);
            bf16x4 b1 = *(const bf16x4*)(wrow + kk + 4);
            bv[0] = b0[0]; bv[1] = b0[1]; bv[2] = b0[2]; bv[3] = b0[3];
            bv[4] = b1[0]; bv[5] = b1[1]; bv[6] = b1[2]; bv[7] = b1[3];
            if (kb + 8 <= F_) {           // kb*4 mult of 32 -> float2 aligned
                float2 p0 = *(const float2*)(xrow + kb);
                float2 p1 = *(const float2*)(xrow + kb + 2);
                float2 p2 = *(const float2*)(xrow + kb + 4);
                float2 p3 = *(const float2*)(xrow + kb + 6);
                av[0] = f2bf(p0.x); av[1] = f2bf(p0.y);
                av[2] = f2bf(p1.x); av[3] = f2bf(p1.y);
                av[4] = f2bf(p2.x); av[5] = f2bf(p2.y);
                av[6] = f2bf(p3.x); av[7] = f2bf(p3.y);
            } else {                      // tail chunks (kb = 240, 248)
                #pragma unroll
                for (int j = 0; j < 8; ++j)
                    av[j] = (kb + j < F_) ? f2bf(xrow[kb + j]) : (short)0;
            }
            acc = __builtin_amdgcn_mfma_f32_16x16x32_bf16(av, bv, acc, 0, 0, 0);
        }
        int col = lane & 15, mb = m0 + quad * 4;
        #pragma unroll
        for (int rr = 0; rr < 4; ++rr)
            PQ[(size_t)(mb + rr) * 64 + n0 + col] = acc[rr];
        return;
    }
    bx -= 50;
    if (bx < 100) {                      // ---- Abuf x staging, 8 rows/block
        int r0 = bx * 8;
        for (int idx = tid; idx < 8 * F_; idx += 256) {
            int lr = idx / F_, k = idx - lr * F_;
            Abuf[(size_t)(r0 + lr) * KX_ + k] = f2bf(x[(size_t)(r0 + lr) * F_ + k]);
        }
        return;
    }
    bx -= 100;
    int tx = tid & 31, ty = tid >> 5;    // 32 x 8
    if (bx < 360) {                      // ---- WoT[n][k] = Wo[k][n]
        int n0 = (bx % 45) * 32, k0 = (bx / 45) * 32;
        #pragma unroll
        for (int r = 0; r < 4; ++r) {
            int k = k0 + ty + r * 8;
            tile[ty + r * 8][tx] = (k < F_) ? f2bf(Wo[k * LBL_ + n0 + tx]) : (short)0;
        }
        __syncthreads();
        #pragma unroll
        for (int r = 0; r < 4; ++r)
            WoT[(size_t)(n0 + ty + r * 8) * KN_ + k0 + tx] = tile[tx][ty + r * 8];
        return;
    }
    bx -= 360;
    {                                    // ---- WnT[n][k] = Wn[k][n] (padded)
        int n0 = (bx % 8) * 32, k0 = (bx / 8) * 32;
        #pragma unroll
        for (int r = 0; r < 4; ++r) {
            int k = k0 + ty + r * 8, n = n0 + tx;
            tile[ty + r * 8][tx] =
                (n < F_ && k < NODE_IN_) ? f2bf(Wn[k * F_ + n]) : (short)0;
        }
        __syncthreads();
        #pragma unroll
        for (int r = 0; r < 4; ++r)
            WnT[(size_t)(n0 + ty + r * 8) * KX_ + k0 + tx] = tile[tx][ty + r * 8];
    }
}

// ---------------------------------------------------------------------------
// K2 k_agg: sparse aggregation (fp32 VALU) -> bf16 agg cols of Abuf.
// grid = 1600 blocks x 256 thr (8 groups x 32 lanes, lane = channel).
// ---------------------------------------------------------------------------
__global__ void k_agg(const float* __restrict__ a, const float* __restrict__ e,
                      const float* __restrict__ Ws, const float* __restrict__ bs,
                      const float* __restrict__ alpha,
                      const float* __restrict__ Wai, const float* __restrict__ bai,
                      const float* __restrict__ Waj, const float* __restrict__ baj,
                      const float* __restrict__ PQ, short* __restrict__ Abuf) {
    int blk  = blockIdx.x;
    int mode = (blk >= B_ * N_) ? 1 : 0;
    int row  = mode ? blk - B_ * N_ : blk;   // b*N + n
    int b = row / N_, n = row % N_;
    int tid = threadIdx.x;
    int c = tid & 31, g = tid >> 5;

    float w3  = Ws[(2 * F_) * C_ + c];
    float w4  = Ws[(2 * F_ + 1) * C_ + c];
    float bsc = bs[c];
    float alc = alpha[c];
    float wat = mode ? Waj[c] : Wai[c];
    float bat = mode ? baj[0] : bai[0];

    float ownc = PQ[(size_t)row * 64 + (mode ? 32 : 0) + c];
    const float* oth = PQ + (size_t)b * N_ * 64 + (mode ? 0 : 32) + c;
    const float* abase = a + (size_t)b * N_ * N_;
    const float* ebase = e + (size_t)b * N_ * N_;

    float acc = 0.f;
    #pragma unroll 4
    for (int m = g; m < N_; m += 8) {
        float aij  = mode ? abase[m * N_ + n] : abase[n * N_ + m];
        float er   = ebase[n * N_ + m];
        float ec   = ebase[m * N_ + n];
        float othv = oth[(size_t)m * 64];
        if (aij != 0.f) {                    // uniform per 32-lane group
            float eij = mode ? ec : er;
            float eji = mode ? er : ec;
            float raw = ownc + othv + eij * w3 + eji * w4 + bsc;
            float s = (raw >= 0.f ? raw : alc * raw) * aij;
            float t2 = s * wat;              // 32-ch butterfly dot
            t2 += __shfl_xor(t2, 1, 32);
            t2 += __shfl_xor(t2, 2, 32);
            t2 += __shfl_xor(t2, 4, 32);
            t2 += __shfl_xor(t2, 8, 32);
            t2 += __shfl_xor(t2, 16, 32);
            float att = 1.f / (1.f + __expf(-(t2 + bat)));
            acc += s * att;
        }
    }
    __shared__ float part[8][C_ + 1];
    part[g][c] = acc;
    __syncthreads();
    if (tid < C_) {
        float tot = 0.f;
        #pragma unroll
        for (int gg = 0; gg < 8; ++gg) tot += part[gg][tid];
        // Abuf agg cols: mode 0 -> 246..277 (agg_i), mode 1 -> 278..309
        Abuf[(size_t)row * KX_ + F_ + mode * C_ + tid] = f2bf(tot);
    }
}

// ---------------------------------------------------------------------------
// K3 k_nodeout: node + out fused at m-tile granularity, BALANCED.
// grid = (50, 6), 1024 thr = 16 waves; block (bx, by): rows m0 = bx*16.
//  phase A: wave w computes node n-tile w (16 tiles = all 256 cols) -> LDS
//  phase B: waves 0..14 each compute 1 out n-tile ((by*15 + w)*16); 6 blocks
//           per m0 cover 90 tiles. Node recomputed 6x (cheap MFMA) to keep
//           300 blocks of parallelism. Xs row stride 264 shorts (528 B:
//           16B-aligned b128, bank start 4r mod 32 -> 2-way alias = free).
// ---------------------------------------------------------------------------
__global__ __launch_bounds__(1024, 1)
void k_nodeout(const short* __restrict__ Abuf, const short* __restrict__ WnT,
               const float* __restrict__ bn, const short* __restrict__ WoT,
               const float* __restrict__ bo, float* __restrict__ out) {
    __shared__ short Xs[16][264];
    int tid = threadIdx.x;
    int w = tid >> 6, lane = tid & 63;
    int m0 = blockIdx.x * 16;
    int col = lane & 15, quad = lane >> 4;

    // phase A: node tile n0 = w*16
    {
        int n0 = w * 16;
        f32x4 acc = mfma_tile<KX_>(Abuf, WnT, m0, n0, lane);
        int nn = n0 + col;
        float bv = (nn < F_) ? bn[nn] : 0.f;
        #pragma unroll
        for (int r = 0; r < 4; ++r)
            Xs[quad * 4 + r][nn] = (nn < F_) ? f2bf(acc[r] + bv) : (short)0;
    }
    __syncthreads();

    // phase B: one out tile per wave (waves 0..14)
    if (w < 15) {
        int n0 = (blockIdx.y * 15 + w) * 16;
        int r = lane & 15;
        const short* ap = &Xs[r][quad * 8];
        const short* bp = WoT + (size_t)(n0 + r) * KN_ + quad * 8;
        f32x4 acc = {0.f, 0.f, 0.f, 0.f};
        #pragma unroll
        for (int kk = 0; kk < KN_; kk += 32) {
            bf16x8 av = *(const bf16x8*)(ap + kk);
            bf16x8 bv = *(const bf16x8*)(bp + kk);
            acc = __builtin_amdgcn_mfma_f32_16x16x32_bf16(av, bv, acc, 0, 0, 0);
        }
        int nn = n0 + col;
        float bv = bo[nn];
        #pragma unroll
        for (int rr = 0; rr < 4; ++rr)
            out[(size_t)(m0 + quad * 4 + rr) * LBL_ + nn] = acc[rr] + bv;
    }
}

// ---------------------------------------------------------------------------
extern "C" void kernel_launch(void* const* d_in, const int* in_sizes, int n_in,
                              void* d_out, int out_size, void* d_ws, size_t ws_size,
                              hipStream_t stream) {
    const float* x   = (const float*)d_in[0];
    const float* a   = (const float*)d_in[1];
    const float* e   = (const float*)d_in[2];
    const float* Ws  = (const float*)d_in[3];
    const float* bs  = (const float*)d_in[4];
    const float* al  = (const float*)d_in[5];
    const float* Wai = (const float*)d_in[6];
    const float* bai = (const float*)d_in[7];
    const float* Waj = (const float*)d_in[8];
    const float* baj = (const float*)d_in[9];
    const float* Wn  = (const float*)d_in[10];
    const float* bn  = (const float*)d_in[11];
    const float* Wo  = (const float*)d_in[12];
    const float* bo  = (const float*)d_in[13];

    float* PQ   = (float*)d_ws;                   // 800*64 f32
    short* Abuf = (short*)(PQ + 800 * 64);        // 800*320 bf16 (16B-aligned)
    short* WnT  = Abuf + T_ABUF;                  // 256*320
    short* WoT  = WnT + T_WNT;                    // 1440*256

    k_pre<<<590, 256, 0, stream>>>(x, Ws, Wn, Wo, PQ, Abuf, WnT, WoT);
    k_agg<<<2 * B_ * N_, 256, 0, stream>>>(a, e, Ws, bs, al, Wai, bai, Waj, baj,
                                           PQ, Abuf);
    k_nodeout<<<dim3(50, 6), 1024, 0, stream>>>(Abuf, WnT, bn, WoT, bo,
                                                (float*)d_out);
}

// Round 15
// 140.947 us; speedup vs baseline: 1.0772x; 1.0772x over previous
//
#include <hip/hip_runtime.h>
#include <math.h>

#define B_ 2
#define N_ 400
#define F_ 246
#define C_ 32
#define LBL_ 1440
#define NODE_IN_ 310  // F + 2C

#define KX_ 320   // Abuf row: 246 x | 32 aggi | 32 aggj | 10 pad (pad holds
                  // poison; consumer weights there are 0.0; bf16 poison is
                  // finite -> 0*poison = 0)
#define KN_ 256   // node output cols padded 246 -> 256

#define T_ABUF (800 * KX_)
#define T_W2T  (64 * KX_)
#define T_WNT  (256 * KX_)
#define T_WOT  (LBL_ * KN_)

typedef __attribute__((ext_vector_type(8))) short bf16x8;  // 8 bf16, 4 VGPRs
typedef __attribute__((ext_vector_type(4))) float f32x4;

__device__ __forceinline__ short f2bf(float f) {           // RNE fp32->bf16
    unsigned u = __float_as_uint(f);
    return (short)((u + 0x7FFF + ((u >> 16) & 1)) >> 16);
}

// MFMA layouts (HW-verified m89/m120): A[m=lane&15][k=quad*8+j];
// BT row-major [n][k] (8 consecutive k per lane); C/D col=lane&15, row=quad*4+reg.
template <int K>
__device__ __forceinline__ f32x4 mfma_tile(const short* __restrict__ A,
                                           const short* __restrict__ BT,
                                           int m0, int n0, int lane) {
    int r = lane & 15, quad = lane >> 4;
    const short* ap = A + (size_t)(m0 + r) * K + quad * 8;
    const short* bp = BT + (size_t)(n0 + r) * K + quad * 8;
    f32x4 acc = {0.f, 0.f, 0.f, 0.f};
    #pragma unroll
    for (int kk = 0; kk < K; kk += 32) {
        bf16x8 av = *(const bf16x8*)(ap + kk);
        bf16x8 bv = *(const bf16x8*)(bp + kk);
        acc = __builtin_amdgcn_mfma_f32_16x16x32_bf16(av, bv, acc, 0, 0, 0);
    }
    return acc;
}

// ---------------------------------------------------------------------------
// K1 k_prep — R12-proven staging (2 KB LDS only; ~8 blocks/CU occupancy):
//   blocks [0,800):     Abuf[row][0:246] = bf16(x row)
//   blocks [800,1160):  WoT[1440][256] = bf16(Wo^T), LDS 32x32 tiles
//   blocks [1160,1240): WnT[256][320]  = bf16(Wn^T) zero-padded, LDS tiles
//   blocks [1240,1320): W2T[64][320]   = [WsP|WsQ]^T zero-padded, linear
// ---------------------------------------------------------------------------
__global__ void k_prep(const float* __restrict__ x, const float* __restrict__ Ws,
                       const float* __restrict__ Wn, const float* __restrict__ Wo,
                       short* __restrict__ Abuf, short* __restrict__ W2T,
                       short* __restrict__ WnT, short* __restrict__ WoT) {
    __shared__ short tile[32][33];
    int bx = blockIdx.x, tid = threadIdx.x;
    if (bx < 800) {
        if (tid < F_) Abuf[bx * KX_ + tid] = f2bf(x[bx * F_ + tid]);
        return;
    }
    bx -= 800;
    int tx = tid & 31, ty = tid >> 5;      // 32 x 8
    if (bx < 360) {                        // WoT[n][k] = Wo[k][n]
        int n0 = (bx % 45) * 32, k0 = (bx / 45) * 32;
        #pragma unroll
        for (int r = 0; r < 4; ++r) {
            int k = k0 + ty + r * 8;
            tile[ty + r * 8][tx] = (k < F_) ? f2bf(Wo[k * LBL_ + n0 + tx]) : (short)0;
        }
        __syncthreads();
        #pragma unroll
        for (int r = 0; r < 4; ++r)
            WoT[(size_t)(n0 + ty + r * 8) * KN_ + k0 + tx] = tile[tx][ty + r * 8];
        return;
    }
    bx -= 360;
    if (bx < 80) {                         // WnT[n][k] = Wn[k][n] (zero-padded)
        int n0 = (bx % 8) * 32, k0 = (bx / 8) * 32;
        #pragma unroll
        for (int r = 0; r < 4; ++r) {
            int k = k0 + ty + r * 8, n = n0 + tx;
            tile[ty + r * 8][tx] =
                (n < F_ && k < NODE_IN_) ? f2bf(Wn[k * F_ + n]) : (short)0;
        }
        __syncthreads();
        #pragma unroll
        for (int r = 0; r < 4; ++r)
            WnT[(size_t)(n0 + ty + r * 8) * KX_ + k0 + tx] = tile[tx][ty + r * 8];
        return;
    }
    bx -= 80;
    {                                      // W2T linear (20480 elems)
        int t = bx * 256 + tid;
        if (t < 64 * KX_) {
            int n = t / KX_, k = t - n * KX_;
            float v = 0.f;
            if (k < F_) v = (n < C_) ? Ws[k * C_ + n] : Ws[(F_ + k) * C_ + (n - C_)];
            W2T[t] = f2bf(v);
        }
    }
}

// K2 k_pq: PQ[800][64] = x @ [WsP|WsQ]  (R12-proven; Abuf pad x W2T zeros = 0)
__global__ void k_pq(const short* __restrict__ Abuf, const short* __restrict__ W2T,
                     float* __restrict__ PQ) {
    int lane = threadIdx.x;
    int m0 = blockIdx.x * 16, n0 = blockIdx.y * 16;
    f32x4 acc = mfma_tile<KX_>(Abuf, W2T, m0, n0, lane);
    int n = n0 + (lane & 15), mb = m0 + (lane >> 4) * 4;
    #pragma unroll
    for (int r = 0; r < 4; ++r)
        PQ[(size_t)(mb + r) * 64 + n] = acc[r];
}

// ---------------------------------------------------------------------------
// K3 k_agg: sparse aggregation (fp32 VALU) -> bf16 agg cols of Abuf.
// grid = 1600 blocks x 256 thr (8 groups x 32 lanes, lane = channel).
// ---------------------------------------------------------------------------
__global__ void k_agg(const float* __restrict__ a, const float* __restrict__ e,
                      const float* __restrict__ Ws, const float* __restrict__ bs,
                      const float* __restrict__ alpha,
                      const float* __restrict__ Wai, const float* __restrict__ bai,
                      const float* __restrict__ Waj, const float* __restrict__ baj,
                      const float* __restrict__ PQ, short* __restrict__ Abuf) {
    int blk  = blockIdx.x;
    int mode = (blk >= B_ * N_) ? 1 : 0;
    int row  = mode ? blk - B_ * N_ : blk;   // b*N + n
    int b = row / N_, n = row % N_;
    int tid = threadIdx.x;
    int c = tid & 31, g = tid >> 5;

    float w3  = Ws[(2 * F_) * C_ + c];
    float w4  = Ws[(2 * F_ + 1) * C_ + c];
    float bsc = bs[c];
    float alc = alpha[c];
    float wat = mode ? Waj[c] : Wai[c];
    float bat = mode ? baj[0] : bai[0];

    float ownc = PQ[(size_t)row * 64 + (mode ? 32 : 0) + c];
    const float* oth = PQ + (size_t)b * N_ * 64 + (mode ? 0 : 32) + c;
    const float* abase = a + (size_t)b * N_ * N_;
    const float* ebase = e + (size_t)b * N_ * N_;

    float acc = 0.f;
    #pragma unroll 4
    for (int m = g; m < N_; m += 8) {
        float aij  = mode ? abase[m * N_ + n] : abase[n * N_ + m];
        float er   = ebase[n * N_ + m];
        float ec   = ebase[m * N_ + n];
        float othv = oth[(size_t)m * 64];
        if (aij != 0.f) {                    // uniform per 32-lane group
            float eij = mode ? ec : er;
            float eji = mode ? er : ec;
            float raw = ownc + othv + eij * w3 + eji * w4 + bsc;
            float s = (raw >= 0.f ? raw : alc * raw) * aij;
            float t2 = s * wat;              // 32-ch butterfly dot
            t2 += __shfl_xor(t2, 1, 32);
            t2 += __shfl_xor(t2, 2, 32);
            t2 += __shfl_xor(t2, 4, 32);
            t2 += __shfl_xor(t2, 8, 32);
            t2 += __shfl_xor(t2, 16, 32);
            float att = 1.f / (1.f + __expf(-(t2 + bat)));
            acc += s * att;
        }
    }
    __shared__ float part[8][C_ + 1];
    part[g][c] = acc;
    __syncthreads();
    if (tid < C_) {
        float tot = 0.f;
        #pragma unroll
        for (int gg = 0; gg < 8; ++gg) tot += part[gg][tid];
        // Abuf agg cols: mode 0 -> 246..277 (agg_i), mode 1 -> 278..309
        Abuf[(size_t)row * KX_ + F_ + mode * C_ + tid] = f2bf(tot);
    }
}

// ---------------------------------------------------------------------------
// K4 k_nodeout: node + out fused at m-tile granularity (R14-validated math,
// small LDS). grid = (50, 6), 1024 thr = 16 waves; rows m0 = bx*16.
//  phase A: wave w computes node n-tile w (16 tiles = 256 cols) -> LDS bf16
//  phase B: waves 0..14 each one out n-tile ((by*15+w)*16); 6 by-blocks
//           cover 90 tiles. Node recomputed 6x (~1 us total MFMA) to keep
//           300 blocks. Xs stride 264 shorts: 16B-aligned b128, bank start
//           4r mod 32 -> 2-way alias only (free, m136).
// ---------------------------------------------------------------------------
__global__ __launch_bounds__(1024, 1)
void k_nodeout(const short* __restrict__ Abuf, const short* __restrict__ WnT,
               const float* __restrict__ bn, const short* __restrict__ WoT,
               const float* __restrict__ bo, float* __restrict__ out) {
    __shared__ short Xs[16][264];          // 8.4 KB
    int tid = threadIdx.x;
    int w = tid >> 6, lane = tid & 63;
    int m0 = blockIdx.x * 16;
    int col = lane & 15, quad = lane >> 4;

    // phase A: node tile n0 = w*16
    {
        int n0 = w * 16;
        f32x4 acc = mfma_tile<KX_>(Abuf, WnT, m0, n0, lane);
        int nn = n0 + col;
        float bv = (nn < F_) ? bn[nn] : 0.f;
        #pragma unroll
        for (int r = 0; r < 4; ++r)
            Xs[quad * 4 + r][nn] = (nn < F_) ? f2bf(acc[r] + bv) : (short)0;
    }
    __syncthreads();

    // phase B: one out tile per wave (waves 0..14)
    if (w < 15) {
        int n0 = (blockIdx.y * 15 + w) * 16;
        int r = lane & 15;
        const short* ap = &Xs[r][quad * 8];
        const short* bp = WoT + (size_t)(n0 + r) * KN_ + quad * 8;
        f32x4 acc = {0.f, 0.f, 0.f, 0.f};
        #pragma unroll
        for (int kk = 0; kk < KN_; kk += 32) {
            bf16x8 av = *(const bf16x8*)(ap + kk);
            bf16x8 bv = *(const bf16x8*)(bp + kk);
            acc = __builtin_amdgcn_mfma_f32_16x16x32_bf16(av, bv, acc, 0, 0, 0);
        }
        int nn = n0 + col;
        float bv = bo[nn];
        #pragma unroll
        for (int rr = 0; rr < 4; ++rr)
            out[(size_t)(m0 + quad * 4 + rr) * LBL_ + nn] = acc[rr] + bv;
    }
}

// ---------------------------------------------------------------------------
extern "C" void kernel_launch(void* const* d_in, const int* in_sizes, int n_in,
                              void* d_out, int out_size, void* d_ws, size_t ws_size,
                              hipStream_t stream) {
    const float* x   = (const float*)d_in[0];
    const float* a   = (const float*)d_in[1];
    const float* e   = (const float*)d_in[2];
    const float* Ws  = (const float*)d_in[3];
    const float* bs  = (const float*)d_in[4];
    const float* al  = (const float*)d_in[5];
    const float* Wai = (const float*)d_in[6];
    const float* bai = (const float*)d_in[7];
    const float* Waj = (const float*)d_in[8];
    const float* baj = (const float*)d_in[9];
    const float* Wn  = (const float*)d_in[10];
    const float* bn  = (const float*)d_in[11];
    const float* Wo  = (const float*)d_in[12];
    const float* bo  = (const float*)d_in[13];

    float* PQ   = (float*)d_ws;                   // 800*64 f32
    short* Abuf = (short*)(PQ + 800 * 64);        // 800*320 bf16 (16B-aligned)
    short* W2T  = Abuf + T_ABUF;                  // 64*320
    short* WnT  = W2T + T_W2T;                    // 256*320
    short* WoT  = WnT + T_WNT;                    // 1440*256

    k_prep<<<1320, 256, 0, stream>>>(x, Ws, Wn, Wo, Abuf, W2T, WnT, WoT);
    k_pq  <<<dim3(50, 4),  64, 0, stream>>>(Abuf, W2T, PQ);
    k_agg <<<2 * B_ * N_, 256, 0, stream>>>(a, e, Ws, bs, al, Wai, bai, Waj, baj,
                                            PQ, Abuf);
    k_nodeout<<<dim3(50, 6), 1024, 0, stream>>>(Abuf, WnT, bn, WoT, bo,
                                                (float*)d_out);
}

// Round 16
// 126.852 us; speedup vs baseline: 1.1969x; 1.1111x over previous
//
#include <hip/hip_runtime.h>
#include <math.h>

#define B_ 2
#define N_ 400
#define F_ 246
#define C_ 32
#define LBL_ 1440
#define NODE_IN_ 310  // F + 2C

#define KX_ 320   // Abuf row: 246 x | 32 aggi | 32 aggj | 10 pad (pad cols
                  // may hold poison: every consumer's weight there is 0.0)
#define KN_ 256   // XNEW padded 246 -> 256

#define T_ABUF (800 * KX_)
#define T_W2T  (64 * KX_)
#define T_WNT  (256 * KX_)
#define T_WOT  (LBL_ * KN_)

typedef __attribute__((ext_vector_type(8))) short bf16x8;  // 8 bf16, 4 VGPRs
typedef __attribute__((ext_vector_type(4))) float f32x4;

__device__ __forceinline__ short f2bf(float f) {           // RNE fp32->bf16
    unsigned u = __float_as_uint(f);
    return (short)((u + 0x7FFF + ((u >> 16) & 1)) >> 16);
}

// ---------------------------------------------------------------------------
// PREP (one dispatch, block ranges). All transposes LDS-tiled: coalesced
// reads AND writes. 2 KB LDS only -> high staging occupancy (R14's 66 KB
// function-scope LDS crushed all 590 blocks' occupancy: -25 us).
//   blocks [0,800):        Abuf[row][0:246] = bf16(x row)
//   blocks [800,1160):     WoT[1440][256] = bf16(Wo^T), 45x8 32x32 tiles
//   blocks [1160,1240):    WnT[256][320]  = bf16(Wn^T) zero-padded
//   blocks [1240,1320):    W2T[64][320]   = [WsP|WsQ]^T zero-padded, linear
// ---------------------------------------------------------------------------
__global__ void k_prep(const float* __restrict__ x, const float* __restrict__ Ws,
                       const float* __restrict__ Wn, const float* __restrict__ Wo,
                       short* __restrict__ Abuf, short* __restrict__ W2T,
                       short* __restrict__ WnT, short* __restrict__ WoT) {
    __shared__ short tile[32][33];
    int bx = blockIdx.x, tid = threadIdx.x;
    if (bx < 800) {
        if (tid < F_) Abuf[bx * KX_ + tid] = f2bf(x[bx * F_ + tid]);
        return;
    }
    bx -= 800;
    int tx = tid & 31, ty = tid >> 5;      // 32 x 8
    if (bx < 360) {                        // WoT[n][k] = Wo[k][n]
        int n0 = (bx % 45) * 32, k0 = (bx / 45) * 32;
        #pragma unroll
        for (int r = 0; r < 4; ++r) {
            int k = k0 + ty + r * 8;
            tile[ty + r * 8][tx] = (k < F_) ? f2bf(Wo[k * LBL_ + n0 + tx]) : (short)0;
        }
        __syncthreads();
        #pragma unroll
        for (int r = 0; r < 4; ++r)
            WoT[(size_t)(n0 + ty + r * 8) * KN_ + k0 + tx] = tile[tx][ty + r * 8];
        return;
    }
    bx -= 360;
    if (bx < 80) {                         // WnT[n][k] = Wn[k][n] (zero-padded)
        int n0 = (bx % 8) * 32, k0 = (bx / 8) * 32;
        #pragma unroll
        for (int r = 0; r < 4; ++r) {
            int k = k0 + ty + r * 8, n = n0 + tx;
            tile[ty + r * 8][tx] =
                (n < F_ && k < NODE_IN_) ? f2bf(Wn[k * F_ + n]) : (short)0;
        }
        __syncthreads();
        #pragma unroll
        for (int r = 0; r < 4; ++r)
            WnT[(size_t)(n0 + ty + r * 8) * KX_ + k0 + tx] = tile[tx][ty + r * 8];
        return;
    }
    bx -= 80;
    {                                      // W2T linear (20480 elems)
        int t = bx * 256 + tid;
        if (t < 64 * KX_) {
            int n = t / KX_, k = t - n * KX_;
            float v = 0.f;
            if (k < F_) v = (n < C_) ? Ws[k * C_ + n] : Ws[(F_ + k) * C_ + (n - C_)];
            W2T[t] = f2bf(v);
        }
    }
}

// ---------------------------------------------------------------------------
// MFMA helpers. Layouts (HW-verified m89/m120): A[m=lane&15][k=quad*8+j];
// BT row-major [n][k]; C/D col=lane&15, row=quad*4+reg.
// ---------------------------------------------------------------------------
template <int K>
__device__ __forceinline__ f32x4 mfma_tile(const short* __restrict__ A,
                                           const short* __restrict__ BT,
                                           int m0, int n0, int lane) {
    int r = lane & 15, quad = lane >> 4;
    const short* ap = A + (size_t)(m0 + r) * K + quad * 8;
    const short* bp = BT + (size_t)(n0 + r) * K + quad * 8;
    f32x4 acc = {0.f, 0.f, 0.f, 0.f};
    #pragma unroll
    for (int kk = 0; kk < K; kk += 32) {
        bf16x8 av = *(const bf16x8*)(ap + kk);
        bf16x8 bv = *(const bf16x8*)(bp + kk);
        acc = __builtin_amdgcn_mfma_f32_16x16x32_bf16(av, bv, acc, 0, 0, 0);
    }
    return acc;
}

// Two n-tiles sharing one A-fragment: -25% loads, 2 independent acc chains.
template <int K>
__device__ __forceinline__ void mfma_tile2(const short* __restrict__ A,
                                           const short* __restrict__ BT,
                                           int m0, int n0, int lane,
                                           f32x4& acc0, f32x4& acc1) {
    int r = lane & 15, quad = lane >> 4;
    const short* ap = A + (size_t)(m0 + r) * K + quad * 8;
    const short* b0 = BT + (size_t)(n0 + r) * K + quad * 8;
    const short* b1 = BT + (size_t)(n0 + 16 + r) * K + quad * 8;
    #pragma unroll
    for (int kk = 0; kk < K; kk += 32) {
        bf16x8 av  = *(const bf16x8*)(ap + kk);
        bf16x8 bv0 = *(const bf16x8*)(b0 + kk);
        bf16x8 bv1 = *(const bf16x8*)(b1 + kk);
        acc0 = __builtin_amdgcn_mfma_f32_16x16x32_bf16(av, bv0, acc0, 0, 0, 0);
        acc1 = __builtin_amdgcn_mfma_f32_16x16x32_bf16(av, bv1, acc1, 0, 0, 0);
    }
}

// K1: PQ[800][64] = x @ [WsP|WsQ]  (fp32; Abuf pad cols x W2T zeros = 0)
__global__ void k_pq(const short* __restrict__ Abuf, const short* __restrict__ W2T,
                     float* __restrict__ PQ) {
    int lane = threadIdx.x;
    int m0 = blockIdx.x * 16, n0 = blockIdx.y * 16;
    f32x4 acc = mfma_tile<KX_>(Abuf, W2T, m0, n0, lane);
    int n = n0 + (lane & 15), mb = m0 + (lane >> 4) * 4;
    #pragma unroll
    for (int r = 0; r < 4; ++r)
        PQ[(size_t)(mb + r) * 64 + n] = acc[r];
}

// ---------------------------------------------------------------------------
// K2: aggregation (sparse, fp32 VALU) -> writes bf16 agg cols of Abuf.
// grid = 1600 blocks x 256 thr (8 groups x 32 lanes, lane = channel).
// ---------------------------------------------------------------------------
__global__ void k_agg(const float* __restrict__ a, const float* __restrict__ e,
                      const float* __restrict__ Ws, const float* __restrict__ bs,
                      const float* __restrict__ alpha,
                      const float* __restrict__ Wai, const float* __restrict__ bai,
                      const float* __restrict__ Waj, const float* __restrict__ baj,
                      const float* __restrict__ PQ, short* __restrict__ Abuf) {
    int blk  = blockIdx.x;
    int mode = (blk >= B_ * N_) ? 1 : 0;
    int row  = mode ? blk - B_ * N_ : blk;   // b*N + n
    int b = row / N_, n = row % N_;
    int tid = threadIdx.x;
    int c = tid & 31, g = tid >> 5;

    float w3  = Ws[(2 * F_) * C_ + c];
    float w4  = Ws[(2 * F_ + 1) * C_ + c];
    float bsc = bs[c];
    float alc = alpha[c];
    float wat = mode ? Waj[c] : Wai[c];
    float bat = mode ? baj[0] : bai[0];

    float ownc = PQ[(size_t)row * 64 + (mode ? 32 : 0) + c];
    const float* oth = PQ + (size_t)b * N_ * 64 + (mode ? 0 : 32) + c;
    const float* abase = a + (size_t)b * N_ * N_;
    const float* ebase = e + (size_t)b * N_ * N_;

    float acc = 0.f;
    #pragma unroll 4
    for (int m = g; m < N_; m += 8) {
        float aij  = mode ? abase[m * N_ + n] : abase[n * N_ + m];
        float er   = ebase[n * N_ + m];
        float ec   = ebase[m * N_ + n];
        float othv = oth[(size_t)m * 64];
        if (aij != 0.f) {                    // uniform per 32-lane group
            float eij = mode ? ec : er;
            float eji = mode ? er : ec;
            float raw = ownc + othv + eij * w3 + eji * w4 + bsc;
            float s = (raw >= 0.f ? raw : alc * raw) * aij;
            float t2 = s * wat;              // 32-ch butterfly dot
            t2 += __shfl_xor(t2, 1, 32);
            t2 += __shfl_xor(t2, 2, 32);
            t2 += __shfl_xor(t2, 4, 32);
            t2 += __shfl_xor(t2, 8, 32);
            t2 += __shfl_xor(t2, 16, 32);
            float att = 1.f / (1.f + __expf(-(t2 + bat)));
            acc += s * att;
        }
    }
    __shared__ float part[8][C_ + 1];
    part[g][c] = acc;
    __syncthreads();
    if (tid < C_) {
        float tot = 0.f;
        #pragma unroll
        for (int gg = 0; gg < 8; ++gg) tot += part[gg][tid];
        // Abuf agg cols: mode 0 -> 246..277 (agg_i), mode 1 -> 278..309
        Abuf[(size_t)row * KX_ + F_ + mode * C_ + tid] = f2bf(tot);
    }
}

// K3: XN16[800][256] = bf16(Abuf @ WnT^T + bn); 2 n-tiles/wave, grid (50,8)
__global__ void k_node(const short* __restrict__ Abuf, const short* __restrict__ WnT,
                       const float* __restrict__ bn, short* __restrict__ XN16) {
    int lane = threadIdx.x;
    int m0 = blockIdx.x * 16, n0 = blockIdx.y * 32;
    f32x4 a0 = {0,0,0,0}, a1 = {0,0,0,0};
    mfma_tile2<KX_>(Abuf, WnT, m0, n0, lane, a0, a1);
    int col = lane & 15, mb = m0 + (lane >> 4) * 4;
    #pragma unroll
    for (int h = 0; h < 2; ++h) {
        int nn = n0 + h * 16 + col;
        f32x4 acc = h ? a1 : a0;
        float bv = (nn < F_) ? bn[nn] : 0.f;
        #pragma unroll
        for (int r = 0; r < 4; ++r)
            XN16[(size_t)(mb + r) * KN_ + nn] =
                (nn < F_) ? f2bf(acc[r] + bv) : (short)0;
    }
}

// K4: out[800][1440] = XN16 @ WoT^T + bo; 2 n-tiles/wave, grid (50,45)
__global__ void k_out(const short* __restrict__ XN16, const short* __restrict__ WoT,
                      const float* __restrict__ bo, float* __restrict__ out) {
    int lane = threadIdx.x;
    int m0 = blockIdx.x * 16, n0 = blockIdx.y * 32;
    f32x4 a0 = {0,0,0,0}, a1 = {0,0,0,0};
    mfma_tile2<KN_>(XN16, WoT, m0, n0, lane, a0, a1);
    int col = lane & 15, mb = m0 + (lane >> 4) * 4;
    #pragma unroll
    for (int h = 0; h < 2; ++h) {
        int nn = n0 + h * 16 + col;
        f32x4 acc = h ? a1 : a0;
        float bv = bo[nn];
        #pragma unroll
        for (int r = 0; r < 4; ++r)
            out[(size_t)(mb + r) * LBL_ + nn] = acc[r] + bv;
    }
}

// ---------------------------------------------------------------------------
extern "C" void kernel_launch(void* const* d_in, const int* in_sizes, int n_in,
                              void* d_out, int out_size, void* d_ws, size_t ws_size,
                              hipStream_t stream) {
    const float* x   = (const float*)d_in[0];
    const float* a   = (const float*)d_in[1];
    const float* e   = (const float*)d_in[2];
    const float* Ws  = (const float*)d_in[3];
    const float* bs  = (const float*)d_in[4];
    const float* al  = (const float*)d_in[5];
    const float* Wai = (const float*)d_in[6];
    const float* bai = (const float*)d_in[7];
    const float* Waj = (const float*)d_in[8];
    const float* baj = (const float*)d_in[9];
    const float* Wn  = (const float*)d_in[10];
    const float* bn  = (const float*)d_in[11];
    const float* Wo  = (const float*)d_in[12];
    const float* bo  = (const float*)d_in[13];

    float* PQ   = (float*)d_ws;                   // 800*64 f32
    short* Abuf = (short*)(PQ + 800 * 64);        // 800*320 bf16 (16B-aligned)
    short* W2T  = Abuf + T_ABUF;                  // 64*320
    short* WnT  = W2T + T_W2T;                    // 256*320
    short* WoT  = WnT + T_WNT;                    // 1440*256
    short* XN16 = WoT + T_WOT;                    // 800*256

    k_prep<<<1320, 256, 0, stream>>>(x, Ws, Wn, Wo, Abuf, W2T, WnT, WoT);
    k_pq  <<<dim3(50, 4),  64, 0, stream>>>(Abuf, W2T, PQ);
    k_agg <<<2 * B_ * N_, 256, 0, stream>>>(a, e, Ws, bs, al, Wai, bai, Waj, baj,
                                            PQ, Abuf);
    k_node<<<dim3(50, 8),  64, 0, stream>>>(Abuf, WnT, bn, XN16);
    k_out <<<dim3(50, 45), 64, 0, stream>>>(XN16, WoT, bo, (float*)d_out);
}